// Round 1
// baseline (235.177 us; speedup 1.0000x reference)
//
#include <hip/hip_runtime.h>
#include <hip/hip_bf16.h>

typedef __attribute__((ext_vector_type(4))) float f32x4;
typedef __attribute__((ext_vector_type(8))) short bf16x8;

#define DINF 1e30f

// ---------------------------------------------------------------------------
// round-to-nearest-even fp32 -> bf16 bits (inputs are finite gaussians)
__device__ __forceinline__ unsigned short f2bf(float f) {
    unsigned int u = __builtin_bit_cast(unsigned int, f);
    u += 0x7FFFu + ((u >> 16) & 1u);
    return (unsigned short)(u >> 16);
}

// ---------------------------------------------------------------------------
// Kernel 1: L2-normalize each 768-dim row, emit bf16.
// grid = 2 * (16*1024 rows) / 4 rows-per-block, block = 256 (4 waves, wave/row)
__global__ __launch_bounds__(256) void norm_bf16_kernel(
    const float* __restrict__ s1, const float* __restrict__ s2,
    __hip_bfloat16* __restrict__ o1, __hip_bfloat16* __restrict__ o2) {
    const int gb = blockIdx.x;
    const float* in;
    __hip_bfloat16* out;
    int rowbase;
    if (gb < 4096) { in = s1; out = o1; rowbase = gb * 4; }
    else           { in = s2; out = o2; rowbase = (gb - 4096) * 4; }
    const int wv = threadIdx.x >> 6;
    const int l  = threadIdx.x & 63;
    const int row = rowbase + wv;

    const float* rp = in + (size_t)row * 768 + l * 4;
    float4 x0 = *(const float4*)(rp);
    float4 x1 = *(const float4*)(rp + 256);
    float4 x2 = *(const float4*)(rp + 512);

    float s = x0.x*x0.x + x0.y*x0.y + x0.z*x0.z + x0.w*x0.w
            + x1.x*x1.x + x1.y*x1.y + x1.z*x1.z + x1.w*x1.w
            + x2.x*x2.x + x2.y*x2.y + x2.z*x2.z + x2.w*x2.w;
#pragma unroll
    for (int off = 32; off > 0; off >>= 1) s += __shfl_xor(s, off, 64);

    const float inv = 1.0f / fmaxf(sqrtf(s), 1e-12f);

    __hip_bfloat16* op = out + (size_t)row * 768 + l * 4;
    ushort4 o;
    o.x = f2bf(x0.x*inv); o.y = f2bf(x0.y*inv); o.z = f2bf(x0.z*inv); o.w = f2bf(x0.w*inv);
    *(ushort4*)(op) = o;
    o.x = f2bf(x1.x*inv); o.y = f2bf(x1.y*inv); o.z = f2bf(x1.z*inv); o.w = f2bf(x1.w*inv);
    *(ushort4*)(op + 256) = o;
    o.x = f2bf(x2.x*inv); o.y = f2bf(x2.y*inv); o.z = f2bf(x2.z*inv); o.w = f2bf(x2.w*inv);
    *(ushort4*)(op + 512) = o;
}

// ---------------------------------------------------------------------------
// Kernel 2: dist[b][i][j] = 1 - dot(s1n[b][i], s2n[b][j])   (bf16 MFMA GEMM)
// 128x128 tile, BK=64, 256 threads (4 waves, each wave a 64x64 quadrant).
// grid = 16 batches * 64 tiles
__global__ __launch_bounds__(256) void gemm_dist_kernel(
    const __hip_bfloat16* __restrict__ A, const __hip_bfloat16* __restrict__ B,
    float* __restrict__ dist) {
    __shared__ __hip_bfloat16 lA[128 * 64];  // [row 0..127][k 0..63], 128B rows
    __shared__ __hip_bfloat16 lB[128 * 64];

    const int blk  = blockIdx.x;
    const int b    = blk >> 6;
    const int tile = blk & 63;
    const int tm = tile >> 3, tn = tile & 7;
    const int tid  = threadIdx.x;
    const int lane = tid & 63, w = tid >> 6;
    const int lr = lane & 15, lg = lane >> 4;
    const int wm = w >> 1, wn = w & 1;

    const __hip_bfloat16* Ab = A + (size_t)b * (1024 * 768) + (size_t)(tm * 128) * 768;
    const __hip_bfloat16* Bb = B + (size_t)b * (1024 * 768) + (size_t)(tn * 128) * 768;

    const int srow = tid >> 3;        // 0..31 (row within 32-row chunk)
    const int scol = (tid & 7) * 8;   // 0..56 (k-octet)

    f32x4 acc[4][4];
#pragma unroll
    for (int m = 0; m < 4; ++m)
#pragma unroll
        for (int n = 0; n < 4; ++n) acc[m][n] = (f32x4){0.f, 0.f, 0.f, 0.f};

    for (int k0 = 0; k0 < 768; k0 += 64) {
        // stage 128x64 bf16 of A and B: each thread one 16B chunk per quarter
        float4 va[4], vb[4];
#pragma unroll
        for (int q = 0; q < 4; ++q) {
            va[q] = *(const float4*)(Ab + (size_t)(q * 32 + srow) * 768 + k0 + scol);
            vb[q] = *(const float4*)(Bb + (size_t)(q * 32 + srow) * 768 + k0 + scol);
        }
#pragma unroll
        for (int q = 0; q < 4; ++q) {
            *(float4*)&lA[q * 2048 + tid * 8] = va[q];
            *(float4*)&lB[q * 2048 + tid * 8] = vb[q];
        }
        __syncthreads();

#pragma unroll
        for (int ks = 0; ks < 64; ks += 32) {
            bf16x8 af[4], bfr[4];
#pragma unroll
            for (int m = 0; m < 4; ++m)
                af[m] = *(const bf16x8*)&lA[(wm * 64 + m * 16 + lr) * 64 + ks + lg * 8];
#pragma unroll
            for (int n = 0; n < 4; ++n)
                bfr[n] = *(const bf16x8*)&lB[(wn * 64 + n * 16 + lr) * 64 + ks + lg * 8];
#pragma unroll
            for (int m = 0; m < 4; ++m)
#pragma unroll
                for (int n = 0; n < 4; ++n)
                    acc[m][n] = __builtin_amdgcn_mfma_f32_16x16x32_bf16(af[m], bfr[n], acc[m][n], 0, 0, 0);
        }
        __syncthreads();
    }

    float* Drow = dist + (size_t)b * (1024 * 1024);
#pragma unroll
    for (int m = 0; m < 4; ++m)
#pragma unroll
        for (int n = 0; n < 4; ++n)
#pragma unroll
            for (int r = 0; r < 4; ++r) {
                const int row = tm * 128 + wm * 64 + m * 16 + lg * 4 + r;
                const int col = tn * 128 + wn * 64 + n * 16 + lr;
                Drow[(size_t)row * 1024 + col] = 1.0f - acc[m][n][r];
            }
}

// ---------------------------------------------------------------------------
// Kernel 3: DTW DP, one wave per batch. Lane t owns cols [16t, 16t+16);
// skewed schedule: step k -> lane t processes row r = k - t.
// left  = dtw[r][16t-1]  = lane(t-1) c_out at step k-1  (shfl_up)
// diag  = dtw[r-1][16t-1]= lane(t-1) c_out at step k-2  (previous shfl)
__global__ __launch_bounds__(64) void dtw_dp_kernel(
    const float* __restrict__ dist, float* __restrict__ out) {
    const int b = blockIdx.x;
    const int t = threadIdx.x;
    const float* Db = dist + (size_t)b * (1024 * 1024) + t * 16;

    float pr[16];
#pragma unroll
    for (int j = 0; j < 16; ++j) pr[j] = DINF;
    float cprev = DINF;  // this lane's dtw[r][last_col] from its previous step
    float dg    = DINF;  // lane(t-1) boundary from two steps ago

    auto LOAD = [&](float4 (&bf)[4], int k) {
        int r = k - t;
        r = r < 0 ? 0 : (r > 1023 ? 1023 : r);
        const float4* p = (const float4*)(Db + (size_t)r * 1024);
#pragma unroll
        for (int i = 0; i < 4; ++i) bf[i] = p[i];
    };

    auto STEP = [&](float4 (&bf)[4], int k) {
        const int r = k - t;
        const bool act = (r >= 0) && (r < 1024);
        float lin = __shfl_up(cprev, 1, 64);
        if (t == 0) lin = DINF;
        float d[16];
#pragma unroll
        for (int i = 0; i < 4; ++i) {
            d[4*i+0] = bf[i].x; d[4*i+1] = bf[i].y; d[4*i+2] = bf[i].z; d[4*i+3] = bf[i].w;
        }
        float c[16];
        float m0 = fminf(fminf(pr[0], dg), lin);
        if (t == 0 && r == 0) m0 = 0.0f;  // dtw[0][0] = dist[0][0]
        c[0] = d[0] + m0;
#pragma unroll
        for (int j = 1; j < 16; ++j)
            c[j] = d[j] + fminf(fminf(pr[j], pr[j-1]), c[j-1]);
        if (act) {
#pragma unroll
            for (int j = 0; j < 16; ++j) pr[j] = c[j];
            cprev = c[15];
        }
        dg = lin;
    };

    float4 b0[4], b1[4], b2[4], b3[4];
    LOAD(b0, 0); LOAD(b1, 1); LOAD(b2, 2); LOAD(b3, 3);

    // steps 0 .. 1087 (last productive step: k = 1023 + 63 = 1086)
#pragma unroll 1
    for (int k = 0; k < 1088; k += 4) {
        STEP(b0, k);     LOAD(b0, k + 4);
        STEP(b1, k + 1); LOAD(b1, k + 5);
        STEP(b2, k + 2); LOAD(b2, k + 6);
        STEP(b3, k + 3); LOAD(b3, k + 7);
    }

    if (t == 63) out[b] = 1.0f / (1.0f + cprev * (1.0f / 2048.0f));
}

// ---------------------------------------------------------------------------
extern "C" void kernel_launch(void* const* d_in, const int* in_sizes, int n_in,
                              void* d_out, int out_size, void* d_ws, size_t ws_size,
                              hipStream_t stream) {
    const float* s1 = (const float*)d_in[0];
    const float* s2 = (const float*)d_in[1];
    float* out = (float*)d_out;

    char* ws = (char*)d_ws;
    __hip_bfloat16* Abf = (__hip_bfloat16*)(ws);                 // 16*1024*768*2 = 25165824
    __hip_bfloat16* Bbf = (__hip_bfloat16*)(ws + 25165824);      // +25165824
    float* dist = (float*)(ws + 50331648);                       // 16*1024*1024*4 = 67108864

    norm_bf16_kernel<<<8192, 256, 0, stream>>>(s1, s2, Abf, Bbf);
    gemm_dist_kernel<<<16 * 64, 256, 0, stream>>>(Abf, Bbf, dist);
    dtw_dp_kernel<<<16, 64, 0, stream>>>(dist, out);
}